// Round 1
// baseline (671.148 us; speedup 1.0000x reference)
//
#include <hip/hip_runtime.h>
#include <hip/hip_bf16.h>
#include <stdint.h>

// Problem constants
#define B_    8
#define T_    4
#define NLAT  64
#define NMED  2048
#define NKV   2112      // NMED + NLAT
#define D_    1024
#define HEADS 16
#define HD    64
#define ADIM  1024
#define BT    32        // B_*T_

typedef __attribute__((ext_vector_type(8))) short bf16x8;
typedef __attribute__((ext_vector_type(4))) float f32x4;

__device__ __forceinline__ ushort f2bf(float f) {
  union { float f; uint32_t u; } v; v.f = f;
  return (ushort)((v.u + 0x7fff + ((v.u >> 16) & 1)) >> 16);
}

__device__ __forceinline__ void gload_lds16(const void* g, void* l) {
  __builtin_amdgcn_global_load_lds(
      (const __attribute__((address_space(1))) void*)g,
      (__attribute__((address_space(3))) void*)l, 16, 0, 0);
}

__device__ __forceinline__ f32x4 mfma16(bf16x8 a, bf16x8 b, f32x4 c) {
  return __builtin_amdgcn_mfma_f32_16x16x32_bf16(a, b, c, 0, 0, 0);
}

// ---------------------------------------------------------------------------
// Weight transpose + f32->bf16: dst[n][k] = src[k][n].  src [K][Nm], 64x64 tiles.
__global__ __launch_bounds__(256) void wtrans(const float* __restrict__ src,
                                              ushort* __restrict__ dst,
                                              int K, int Nm) {
  __shared__ float t[64][65];
  const int tr = blockIdx.y, tc = blockIdx.x;
  const int c = threadIdx.x & 63;
  const int r4 = threadIdx.x >> 6;
#pragma unroll
  for (int rr = 0; rr < 16; ++rr) {
    int r = r4 + rr * 4;
    t[r][c] = src[(size_t)(tr * 64 + r) * Nm + tc * 64 + c];
  }
  __syncthreads();
#pragma unroll
  for (int rr = 0; rr < 16; ++rr) {
    int n = r4 + rr * 4;
    dst[(size_t)(tc * 64 + n) * K + tr * 64 + c] = f2bf(t[c][n]);
  }
}

// ---------------------------------------------------------------------------
// LayerNorm -> bf16, writing concatenated kv_in: rows [bt][0..2047]=LN(x),
// rows [bt][2048..2111]=LN(latents). One block per row, 256 thr x 4 elems.
__global__ __launch_bounds__(256) void ln_kernel(
    const float* __restrict__ lat, const float* __restrict__ x,
    const float* __restrict__ lnl_w, const float* __restrict__ lnl_b,
    const float* __restrict__ lnm_w, const float* __restrict__ lnm_b,
    ushort* __restrict__ kvin) {
  const int row = blockIdx.x;
  const int bt = row / NKV;
  const int j = row - bt * NKV;
  const float* src;
  const float* w;
  const float* bb;
  if (j < NMED) {
    src = x + ((size_t)bt * NMED + j) * D_;
    w = lnm_w; bb = lnm_b;
  } else {
    src = lat + ((size_t)bt * NLAT + (j - NMED)) * D_;
    w = lnl_w; bb = lnl_b;
  }
  const int tid = threadIdx.x;
  float4 v = ((const float4*)src)[tid];
  float s = v.x + v.y + v.z + v.w;
  float s2 = v.x * v.x + v.y * v.y + v.z * v.z + v.w * v.w;
#pragma unroll
  for (int off = 1; off < 64; off <<= 1) {
    s += __shfl_xor(s, off, 64);
    s2 += __shfl_xor(s2, off, 64);
  }
  __shared__ float red[8];
  const int wave = tid >> 6;
  if ((tid & 63) == 0) { red[wave] = s; red[4 + wave] = s2; }
  __syncthreads();
  float S = red[0] + red[1] + red[2] + red[3];
  float S2 = red[4] + red[5] + red[6] + red[7];
  const float inv = 1.f / (float)D_;
  float mu = S * inv;
  float var = S2 * inv - mu * mu;
  float rs = rsqrtf(var + 1e-5f);
  float4 wv = ((const float4*)w)[tid];
  float4 bv = ((const float4*)bb)[tid];
  ushort4 ov;
  ov.x = f2bf((v.x - mu) * rs * wv.x + bv.x);
  ov.y = f2bf((v.y - mu) * rs * wv.y + bv.y);
  ov.z = f2bf((v.z - mu) * rs * wv.z + bv.z);
  ov.w = f2bf((v.w - mu) * rs * wv.w + bv.w);
  ((ushort4*)(kvin + (size_t)row * D_))[tid] = ov;
}

// ---------------------------------------------------------------------------
// m97-structure GEMM: C[M][ldc] = A[M][K] * Bt[N][K]^T.  128x128 tile, BK=32,
// 4 waves (2x2 of 64x64), global_load_lds width-16 staging, 16x16x32 bf16 MFMA.
// AMODE:  0 = direct rows; 1 = q-GEMM remap (row -> kvin[bt*2112+2048+local])
// OUTMODE:0 = bf16; 1 = bf16 * 0.125 (q scale); 2 = f32 + bias
template <int AMODE, int OUTMODE>
__global__ __launch_bounds__(256) void gemm_bt(const ushort* __restrict__ A,
                                               const ushort* __restrict__ Bt,
                                               void* __restrict__ C,
                                               const float* __restrict__ bias,
                                               int M, int N, int K, int ldc) {
  __shared__ ushort lsA[128 * 32];
  __shared__ ushort lsB[128 * 32];
  const int tid = threadIdx.x;
  const int lane = tid & 63;
  const int wave = tid >> 6;
  const int brow = blockIdx.y * 128;
  const int bcol = blockIdx.x * 128;
  const int wr = (wave >> 1) * 64;
  const int wc = (wave & 1) * 64;
  const int lr = lane & 15;
  const int lk = (lane >> 4) * 8;

  f32x4 acc[4][4];
#pragma unroll
  for (int m = 0; m < 4; ++m)
#pragma unroll
    for (int n = 0; n < 4; ++n) acc[m][n] = (f32x4){0.f, 0.f, 0.f, 0.f};

  const int wbase = (tid & 192) * 16;  // wave-uniform LDS byte base (lane*16 implicit)

  for (int k0 = 0; k0 < K; k0 += 32) {
#pragma unroll
    for (int i = 0; i < 2; ++i) {
      int idx = i * 256 + tid;
      int r = idx >> 2;
      int cc = (idx & 3) * 8;
      long arow;
      if (AMODE == 1) {
        int gr = brow + r;
        arow = (long)(gr >> 6) * NKV + NMED + (gr & 63);
      } else {
        arow = brow + r;
      }
      gload_lds16(A + arow * (long)K + k0 + cc, (char*)lsA + i * 4096 + wbase);
      gload_lds16(Bt + (long)(bcol + r) * K + k0 + cc, (char*)lsB + i * 4096 + wbase);
    }
    __syncthreads();  // compiler drains vmcnt before barrier

    bf16x8 af[4], bf[4];
#pragma unroll
    for (int m = 0; m < 4; ++m)
      af[m] = *(const bf16x8*)&lsA[(wr + m * 16 + lr) * 32 + lk];
#pragma unroll
    for (int n = 0; n < 4; ++n)
      bf[n] = *(const bf16x8*)&lsB[(wc + n * 16 + lr) * 32 + lk];
#pragma unroll
    for (int m = 0; m < 4; ++m)
#pragma unroll
      for (int n = 0; n < 4; ++n) acc[m][n] = mfma16(af[m], bf[n], acc[m][n]);
    __syncthreads();
  }

  // Epilogue: D row = 4*(lane>>4)+r, col = lane&15 (verified m89/m91 layout)
#pragma unroll
  for (int m = 0; m < 4; ++m) {
#pragma unroll
    for (int n = 0; n < 4; ++n) {
      int row0 = brow + wr + m * 16 + (lane >> 4) * 4;
      int col = bcol + wc + n * 16 + lr;
#pragma unroll
      for (int r = 0; r < 4; ++r) {
        long off = (long)(row0 + r) * ldc + col;
        float v = acc[m][n][r];
        if (OUTMODE == 0) ((ushort*)C)[off] = f2bf(v);
        else if (OUTMODE == 1) ((ushort*)C)[off] = f2bf(v * 0.125f);
        else ((float*)C)[off] = v + bias[col];
      }
    }
  }
}

// ---------------------------------------------------------------------------
// Flash attention: one block per (bt, h). 4 waves x 16 q-rows. 33 j-tiles of 64.
// q pre-scaled by 0.125.  kv layout: [bt*2112+j][0:1024]=k, [1024:2048]=v.
__global__ __launch_bounds__(256) void attn_kernel(const ushort* __restrict__ q,
                                                   const ushort* __restrict__ kv,
                                                   ushort* __restrict__ o) {
  const int blk = blockIdx.x;
  const int bt = blk >> 4;
  const int h = blk & 15;
  const int tid = threadIdx.x;
  const int wave = tid >> 6;
  const int lane = tid & 63;
  const int lr = lane & 15;
  const int lg = lane >> 4;

  __shared__ ushort vt[64][72];      // V^T tile, padded (+8) for bank spread
  __shared__ ushort pl[4][16][72];   // per-wave P tile, padded

  const ushort* qbase = q + (size_t)(bt * 64 + wave * 16) * ADIM + h * HD;
  bf16x8 qf[2];
#pragma unroll
  for (int ks = 0; ks < 2; ++ks)
    qf[ks] = *(const bf16x8*)(qbase + (size_t)lr * ADIM + ks * 32 + lg * 8);

  const ushort* kvb = kv + (size_t)bt * NKV * 2048;

  f32x4 accO[4];
#pragma unroll
  for (int n = 0; n < 4; ++n) accO[n] = (f32x4){0.f, 0.f, 0.f, 0.f};
  float mrun[4] = {-1e30f, -1e30f, -1e30f, -1e30f};
  float lrun[4] = {0.f, 0.f, 0.f, 0.f};

  for (int jt = 0; jt < NKV / 64; ++jt) {
    const int j0 = jt * 64;
    __syncthreads();  // previous tile's vt/pl fully consumed

    // Stage V^T: vt[d][j] = v[j0+j][h*64+d]
    {
      int jj = tid >> 2;
      int dbase = (tid & 3) * 16;
#pragma unroll
      for (int half = 0; half < 2; ++half) {
        int d0 = dbase + half * 8;
        bf16x8 vv = *(const bf16x8*)(kvb + (size_t)(j0 + jj) * 2048 + ADIM + h * HD + d0);
#pragma unroll
        for (int e = 0; e < 8; ++e) vt[d0 + e][jj] = ((const ushort*)&vv)[e];
      }
    }

    // S = q @ k^T  (k frags straight from global; L1/L2 absorb 4-wave reuse)
    f32x4 s[4];
#pragma unroll
    for (int nj = 0; nj < 4; ++nj) s[nj] = (f32x4){0.f, 0.f, 0.f, 0.f};
#pragma unroll
    for (int nj = 0; nj < 4; ++nj)
#pragma unroll
      for (int ks = 0; ks < 2; ++ks) {
        bf16x8 kf = *(const bf16x8*)(kvb + (size_t)(j0 + nj * 16 + lr) * 2048 +
                                     h * HD + ks * 32 + lg * 8);
        s[nj] = mfma16(qf[ks], kf, s[nj]);
      }

    // Online softmax over this wave's 16 rows (row = 4*lg + r)
    float mt[4], corr[4], psum[4];
#pragma unroll
    for (int r = 0; r < 4; ++r) {
      mt[r] = fmaxf(fmaxf(s[0][r], s[1][r]), fmaxf(s[2][r], s[3][r]));
    }
#pragma unroll
    for (int off = 1; off < 16; off <<= 1)
#pragma unroll
      for (int r = 0; r < 4; ++r) mt[r] = fmaxf(mt[r], __shfl_xor(mt[r], off, 64));
#pragma unroll
    for (int r = 0; r < 4; ++r) {
      float mn = fmaxf(mrun[r], mt[r]);
      corr[r] = __expf(mrun[r] - mn);
      mrun[r] = mn;
      psum[r] = 0.f;
    }
#pragma unroll
    for (int nj = 0; nj < 4; ++nj)
#pragma unroll
      for (int r = 0; r < 4; ++r) {
        float p = __expf(s[nj][r] - mrun[r]);
        s[nj][r] = p;
        psum[r] += p;
      }
#pragma unroll
    for (int off = 1; off < 16; off <<= 1)
#pragma unroll
      for (int r = 0; r < 4; ++r) psum[r] += __shfl_xor(psum[r], off, 64);
#pragma unroll
    for (int r = 0; r < 4; ++r) lrun[r] = lrun[r] * corr[r] + psum[r];
#pragma unroll
    for (int n = 0; n < 4; ++n)
#pragma unroll
      for (int r = 0; r < 4; ++r) accO[n][r] *= corr[r];

    // P -> LDS (per-wave region), then PV
#pragma unroll
    for (int nj = 0; nj < 4; ++nj)
#pragma unroll
      for (int r = 0; r < 4; ++r)
        pl[wave][lg * 4 + r][nj * 16 + lr] = f2bf(s[nj][r]);
    __syncthreads();  // vt + pl visible

    bf16x8 pf[2];
#pragma unroll
    for (int ks = 0; ks < 2; ++ks)
      pf[ks] = *(const bf16x8*)&pl[wave][lr][ks * 32 + lg * 8];
#pragma unroll
    for (int nd = 0; nd < 4; ++nd)
#pragma unroll
      for (int ks = 0; ks < 2; ++ks) {
        bf16x8 vf = *(const bf16x8*)&vt[nd * 16 + lr][ks * 32 + lg * 8];
        accO[nd] = mfma16(pf[ks], vf, accO[nd]);
      }
  }

  // O = accO / l
#pragma unroll
  for (int nd = 0; nd < 4; ++nd)
#pragma unroll
    for (int r = 0; r < 4; ++r) {
      float v = accO[nd][r] / lrun[r];
      int row = bt * 64 + wave * 16 + lg * 4 + r;
      o[(size_t)row * ADIM + h * HD + nd * 16 + lr] = f2bf(v);
    }
}

// ---------------------------------------------------------------------------
extern "C" void kernel_launch(void* const* d_in, const int* in_sizes, int n_in,
                              void* d_out, int out_size, void* d_ws, size_t ws_size,
                              hipStream_t stream) {
  const float* latents = (const float*)d_in[0];
  const float* x = (const float*)d_in[1];
  const float* Wq = (const float*)d_in[2];
  const float* Wkv = (const float*)d_in[3];
  const float* Wout = (const float*)d_in[4];
  const float* bout = (const float*)d_in[5];
  const float* lnl_w = (const float*)d_in[6];
  const float* lnl_b = (const float*)d_in[7];
  const float* lnm_w = (const float*)d_in[8];
  const float* lnm_b = (const float*)d_in[9];

  char* ws = (char*)d_ws;
  size_t off = 0;
  auto alloc = [&](size_t bytes) -> void* {
    void* p = ws + off;
    off += (bytes + 255) & ~(size_t)255;
    return p;
  };
  ushort* kvin = (ushort*)alloc((size_t)BT * NKV * D_ * 2);      // 138.4 MB
  ushort* kvo  = (ushort*)alloc((size_t)BT * NKV * 2048 * 2);    // 276.8 MB
  ushort* qb   = (ushort*)alloc((size_t)BT * NLAT * ADIM * 2);   // 4 MB
  ushort* ao   = (ushort*)alloc((size_t)BT * NLAT * ADIM * 2);   // 4 MB
  ushort* WqT  = (ushort*)alloc((size_t)D_ * ADIM * 2);          // 2 MB
  ushort* WkvT = (ushort*)alloc((size_t)D_ * 2 * ADIM * 2);      // 4 MB
  ushort* WoutT = (ushort*)alloc((size_t)ADIM * D_ * 2);         // 2 MB

  // 1) weights -> bf16 B^T
  wtrans<<<dim3(ADIM / 64, D_ / 64), 256, 0, stream>>>(Wq, WqT, D_, ADIM);
  wtrans<<<dim3(2 * ADIM / 64, D_ / 64), 256, 0, stream>>>(Wkv, WkvT, D_, 2 * ADIM);
  wtrans<<<dim3(D_ / 64, ADIM / 64), 256, 0, stream>>>(Wout, WoutT, ADIM, D_);

  // 2) LN -> bf16 kv_in (med rows then lat rows per bt)
  ln_kernel<<<BT * NKV, 256, 0, stream>>>(latents, x, lnl_w, lnl_b, lnm_w, lnm_b, kvin);

  // 3) q = lat_ln @ Wq  (row-remapped A, 0.125 scale folded in)
  gemm_bt<1, 1><<<dim3(ADIM / 128, BT * NLAT / 128), 256, 0, stream>>>(
      kvin, WqT, qb, nullptr, BT * NLAT, ADIM, D_, ADIM);

  // 4) kv = kv_in @ Wkv  (the big GEMM: 283.5 GF)
  gemm_bt<0, 0><<<dim3(2048 / 128, BT * NKV / 128), 256, 0, stream>>>(
      kvin, WkvT, kvo, nullptr, BT * NKV, 2048, D_, 2048);

  // 5) attention
  attn_kernel<<<BT * HEADS, 256, 0, stream>>>(qb, kvo, ao);

  // 6) out = ao @ Wout + bout  (f32 -> d_out)
  gemm_bt<0, 2><<<dim3(D_ / 128, BT * NLAT / 128), 256, 0, stream>>>(
      ao, WoutT, d_out, bout, BT * NLAT, D_, ADIM, D_);
}

// Round 2
// 596.438 us; speedup vs baseline: 1.1253x; 1.1253x over previous
//
#include <hip/hip_runtime.h>
#include <hip/hip_bf16.h>
#include <stdint.h>

// Problem constants
#define B_    8
#define T_    4
#define NLAT  64
#define NMED  2048
#define NKV   2112      // NMED + NLAT
#define D_    1024
#define HEADS 16
#define HD    64
#define ADIM  1024
#define BT    32        // B_*T_

#define GK    1024      // kv-GEMM K
#define GN    2048      // kv-GEMM N
#define MT256 264       // M tiles of 256 (67584/256)

typedef __attribute__((ext_vector_type(8))) short bf16x8;
typedef __attribute__((ext_vector_type(4))) float f32x4;

__device__ __forceinline__ ushort f2bf(float f) {
  union { float f; uint32_t u; } v; v.f = f;
  return (ushort)((v.u + 0x7fff + ((v.u >> 16) & 1)) >> 16);
}

__device__ __forceinline__ void gload_lds16(const void* g, void* l) {
  __builtin_amdgcn_global_load_lds(
      (const __attribute__((address_space(1))) void*)g,
      (__attribute__((address_space(3))) void*)l, 16, 0, 0);
}

__device__ __forceinline__ f32x4 mfma16(bf16x8 a, bf16x8 b, f32x4 c) {
  return __builtin_amdgcn_mfma_f32_16x16x32_bf16(a, b, c, 0, 0, 0);
}

// ---------------------------------------------------------------------------
// Weight transpose + f32->bf16: dst[n][k] = src[k][n].  src [K][Nm], 64x64 tiles.
__global__ __launch_bounds__(256) void wtrans(const float* __restrict__ src,
                                              ushort* __restrict__ dst,
                                              int K, int Nm) {
  __shared__ float t[64][65];
  const int tr = blockIdx.y, tc = blockIdx.x;
  const int c = threadIdx.x & 63;
  const int r4 = threadIdx.x >> 6;
#pragma unroll
  for (int rr = 0; rr < 16; ++rr) {
    int r = r4 + rr * 4;
    t[r][c] = src[(size_t)(tr * 64 + r) * Nm + tc * 64 + c];
  }
  __syncthreads();
#pragma unroll
  for (int rr = 0; rr < 16; ++rr) {
    int n = r4 + rr * 4;
    dst[(size_t)(tc * 64 + n) * K + tr * 64 + c] = f2bf(t[c][n]);
  }
}

// ---------------------------------------------------------------------------
// LayerNorm -> bf16, writing concatenated kv_in.
__global__ __launch_bounds__(256) void ln_kernel(
    const float* __restrict__ lat, const float* __restrict__ x,
    const float* __restrict__ lnl_w, const float* __restrict__ lnl_b,
    const float* __restrict__ lnm_w, const float* __restrict__ lnm_b,
    ushort* __restrict__ kvin) {
  const int row = blockIdx.x;
  const int bt = row / NKV;
  const int j = row - bt * NKV;
  const float* src;
  const float* w;
  const float* bb;
  if (j < NMED) {
    src = x + ((size_t)bt * NMED + j) * D_;
    w = lnm_w; bb = lnm_b;
  } else {
    src = lat + ((size_t)bt * NLAT + (j - NMED)) * D_;
    w = lnl_w; bb = lnl_b;
  }
  const int tid = threadIdx.x;
  float4 v = ((const float4*)src)[tid];
  float s = v.x + v.y + v.z + v.w;
  float s2 = v.x * v.x + v.y * v.y + v.z * v.z + v.w * v.w;
#pragma unroll
  for (int off = 1; off < 64; off <<= 1) {
    s += __shfl_xor(s, off, 64);
    s2 += __shfl_xor(s2, off, 64);
  }
  __shared__ float red[8];
  const int wave = tid >> 6;
  if ((tid & 63) == 0) { red[wave] = s; red[4 + wave] = s2; }
  __syncthreads();
  float S = red[0] + red[1] + red[2] + red[3];
  float S2 = red[4] + red[5] + red[6] + red[7];
  const float inv = 1.f / (float)D_;
  float mu = S * inv;
  float var = S2 * inv - mu * mu;
  float rs = rsqrtf(var + 1e-5f);
  float4 wv = ((const float4*)w)[tid];
  float4 bv = ((const float4*)bb)[tid];
  ushort4 ov;
  ov.x = f2bf((v.x - mu) * rs * wv.x + bv.x);
  ov.y = f2bf((v.y - mu) * rs * wv.y + bv.y);
  ov.z = f2bf((v.z - mu) * rs * wv.z + bv.z);
  ov.w = f2bf((v.w - mu) * rs * wv.w + bv.w);
  ((ushort4*)(kvin + (size_t)row * D_))[tid] = ov;
}

// ---------------------------------------------------------------------------
// m97-structure 128x128 GEMM — used for the two SMALL GEMMs (q, out).
// AMODE:  0 = direct rows; 1 = q-GEMM remap (row -> kvin[bt*2112+2048+local])
// OUTMODE:1 = bf16 * 0.125 (q scale); 2 = f32 + bias
template <int AMODE, int OUTMODE>
__global__ __launch_bounds__(256) void gemm_bt(const ushort* __restrict__ A,
                                               const ushort* __restrict__ Bt,
                                               void* __restrict__ C,
                                               const float* __restrict__ bias,
                                               int M, int N, int K, int ldc) {
  __shared__ ushort lsA[128 * 32];
  __shared__ ushort lsB[128 * 32];
  const int tid = threadIdx.x;
  const int lane = tid & 63;
  const int wave = tid >> 6;
  const int brow = blockIdx.y * 128;
  const int bcol = blockIdx.x * 128;
  const int wr = (wave >> 1) * 64;
  const int wc = (wave & 1) * 64;
  const int lr = lane & 15;
  const int lk = (lane >> 4) * 8;

  f32x4 acc[4][4];
#pragma unroll
  for (int m = 0; m < 4; ++m)
#pragma unroll
    for (int n = 0; n < 4; ++n) acc[m][n] = (f32x4){0.f, 0.f, 0.f, 0.f};

  const int wbase = (tid & 192) * 16;

  for (int k0 = 0; k0 < K; k0 += 32) {
#pragma unroll
    for (int i = 0; i < 2; ++i) {
      int idx = i * 256 + tid;
      int r = idx >> 2;
      int cc = (idx & 3) * 8;
      long arow;
      if (AMODE == 1) {
        int gr = brow + r;
        arow = (long)(gr >> 6) * NKV + NMED + (gr & 63);
      } else {
        arow = brow + r;
      }
      gload_lds16(A + arow * (long)K + k0 + cc, (char*)lsA + i * 4096 + wbase);
      gload_lds16(Bt + (long)(bcol + r) * K + k0 + cc, (char*)lsB + i * 4096 + wbase);
    }
    __syncthreads();

    bf16x8 af[4], bf[4];
#pragma unroll
    for (int m = 0; m < 4; ++m)
      af[m] = *(const bf16x8*)&lsA[(wr + m * 16 + lr) * 32 + lk];
#pragma unroll
    for (int n = 0; n < 4; ++n)
      bf[n] = *(const bf16x8*)&lsB[(wc + n * 16 + lr) * 32 + lk];
#pragma unroll
    for (int m = 0; m < 4; ++m)
#pragma unroll
      for (int n = 0; n < 4; ++n) acc[m][n] = mfma16(af[m], bf[n], acc[m][n]);
    __syncthreads();
  }

#pragma unroll
  for (int m = 0; m < 4; ++m) {
#pragma unroll
    for (int n = 0; n < 4; ++n) {
      int row0 = brow + wr + m * 16 + (lane >> 4) * 4;
      int col = bcol + wc + n * 16 + lr;
#pragma unroll
      for (int r = 0; r < 4; ++r) {
        long off = (long)(row0 + r) * ldc + col;
        float v = acc[m][n][r];
        if (OUTMODE == 1) ((ushort*)C)[off] = f2bf(v * 0.125f);
        else ((float*)C)[off] = v + bias[col];
      }
    }
  }
}

// ---------------------------------------------------------------------------
// 256x256 deep-pipelined GEMM for kv = kvin @ WkvT^T  (bf16 out).
// 8 waves (2M x 4N), BK=32, 3 LDS buffers (96 KB), prefetch distance 2,
// counted vmcnt(4) per K-tile (never 0 in the loop), XOR chunk swizzle
// (both-sides), swapped MFMA operands for coalesced ushort4 C-stores.
__global__ __launch_bounds__(512, 2) void gemm256(const ushort* __restrict__ A,
                                                  const ushort* __restrict__ Bt,
                                                  ushort* __restrict__ C) {
  extern __shared__ __align__(16) char smem[];  // 3 * (16KB A + 16KB B)
  const int tid = threadIdx.x;
  const int lane = tid & 63;
  const int wv = tid >> 6;   // 0..7
  const int wm = wv >> 2;    // 0..1  (M half: 128 rows)
  const int wn = wv & 3;     // 0..3  (N quarter: 64 cols)
  const int lr = lane & 15;
  const int lg = lane >> 4;

  // bijective XCD swizzle: nwg = 2112 = 8 * 264
  const int g = blockIdx.x;
  const int v = (g & 7) * (MT256 * 8 / 8) + (g >> 3);
  const int bx = v & 7;        // N tile (fast -> A-panel reuse within XCD chunk)
  const int by = v >> 3;       // M tile
  const long brow = (long)by * 256;
  const int bcol = bx * 256;

  const int pcx = lg ^ ((lr >> 1) & 3);  // physical 16B-chunk for frag reads

  f32x4 acc[8][4];
#pragma unroll
  for (int m = 0; m < 8; ++m)
#pragma unroll
    for (int n = 0; n < 4; ++n) acc[m][n] = (f32x4){0.f, 0.f, 0.f, 0.f};

  // staging: phys slot s (0..1023) -> row = s>>2, phys chunk = s&3,
  // logical chunk = (s&3) ^ ((s>>3)&3)  (inverse of read-side swizzle)
  const int s0 = tid;          // load 0 slot
  const int s1 = 512 + tid;    // load 1 slot
  const int r0 = s0 >> 2, lc0 = (s0 & 3) ^ ((s0 >> 3) & 3);
  const int r1 = s1 >> 2, lc1 = (s1 & 3) ^ ((s1 >> 3) & 3);
  const int ldsoff0 = ((s0 >> 6) << 6) * 16;  // wave-uniform part: (l*512+wv*64)*16
  const int ldsoff1 = ((s1 >> 6) << 6) * 16;

#define STAGE_A(buf, kt)                                                        \
  {                                                                             \
    long k0 = (long)(kt) * 32;                                                  \
    char* db = smem + (buf) * 32768;                                            \
    gload_lds16(A + (brow + r0) * GK + k0 + lc0 * 8, db + ldsoff0);             \
    gload_lds16(A + (brow + r1) * GK + k0 + lc1 * 8, db + ldsoff1);             \
  }
#define STAGE_B(buf, kt)                                                        \
  {                                                                             \
    long k0 = (long)(kt) * 32;                                                  \
    char* db = smem + (buf) * 32768 + 16384;                                    \
    gload_lds16(Bt + (long)(bcol + r0) * GK + k0 + lc0 * 8, db + ldsoff0);      \
    gload_lds16(Bt + (long)(bcol + r1) * GK + k0 + lc1 * 8, db + ldsoff1);      \
  }

  // prologue: tiles 0,1 -> bufs 0,1; wait until tile 0 landed (4 newest in flight)
  STAGE_A(0, 0); STAGE_B(0, 0);
  STAGE_A(1, 1); STAGE_B(1, 1);
  asm volatile("s_waitcnt vmcnt(4)" ::: "memory");
  __builtin_amdgcn_s_barrier();
  __builtin_amdgcn_sched_barrier(0);

  int p = 0;
  for (int t = 0; t < GK / 32; ++t) {
    int q = p + 2; if (q >= 3) q -= 3;                 // buffer of tile t+2 (== t-1's)
    int ts = (t + 2 < GK / 32) ? t + 2 : t;            // clamp: dummy re-stage at tail
    const char* bufA = smem + p * 32768;
    const char* bufB = bufA + 16384;
    bf16x8 af[4], bf[4];

    // ---- phase 0: m=0..3 quadrant ----
#pragma unroll
    for (int m = 0; m < 4; ++m) {
      int row = wm * 128 + m * 16 + lr;
      af[m] = *(const bf16x8*)(bufA + row * 64 + pcx * 16);
    }
#pragma unroll
    for (int n = 0; n < 4; ++n) {
      int row = wn * 64 + n * 16 + lr;
      bf[n] = *(const bf16x8*)(bufB + row * 64 + pcx * 16);
    }
    STAGE_A(q, ts);
    __builtin_amdgcn_sched_barrier(0);
    __builtin_amdgcn_s_barrier();
    __builtin_amdgcn_s_setprio(1);
#pragma unroll
    for (int m = 0; m < 4; ++m)
#pragma unroll
      for (int n = 0; n < 4; ++n)
        acc[m][n] = mfma16(bf[n], af[m], acc[m][n]);   // swapped operands
    __builtin_amdgcn_s_setprio(0);
    __builtin_amdgcn_sched_barrier(0);
    __builtin_amdgcn_s_barrier();

    // ---- phase 1: m=4..7 quadrant (bf reused in regs) ----
#pragma unroll
    for (int m = 0; m < 4; ++m) {
      int row = wm * 128 + (m + 4) * 16 + lr;
      af[m] = *(const bf16x8*)(bufA + row * 64 + pcx * 16);
    }
    STAGE_B(q, ts);
    __builtin_amdgcn_sched_barrier(0);
    __builtin_amdgcn_s_barrier();
    __builtin_amdgcn_s_setprio(1);
#pragma unroll
    for (int m = 0; m < 4; ++m)
#pragma unroll
      for (int n = 0; n < 4; ++n)
        acc[m + 4][n] = mfma16(bf[n], af[m], acc[m + 4][n]);
    __builtin_amdgcn_s_setprio(0);
    // counted wait: tile t+1 (issued last iter) landed; tile t+2's 4 stay in flight
    asm volatile("s_waitcnt vmcnt(4)" ::: "memory");
    __builtin_amdgcn_sched_barrier(0);
    __builtin_amdgcn_s_barrier();
    __builtin_amdgcn_sched_barrier(0);
    p = p + 1; if (p >= 3) p -= 3;
  }
#undef STAGE_A
#undef STAGE_B

  // epilogue: lane owns row = ...+lr (fixed), 4 consecutive cols per frag
#pragma unroll
  for (int m = 0; m < 8; ++m) {
    long row = brow + wm * 128 + m * 16 + lr;
    ushort* crow = C + row * GN + bcol + wn * 64 + lg * 4;
#pragma unroll
    for (int n = 0; n < 4; ++n) {
      ushort4 o;
      o.x = f2bf(acc[m][n][0]);
      o.y = f2bf(acc[m][n][1]);
      o.z = f2bf(acc[m][n][2]);
      o.w = f2bf(acc[m][n][3]);
      *(ushort4*)(crow + n * 16) = o;
    }
  }
}

// ---------------------------------------------------------------------------
// Flash attention: one block per (bt, h). 4 waves x 16 q-rows. 33 j-tiles of 64.
__global__ __launch_bounds__(256) void attn_kernel(const ushort* __restrict__ q,
                                                   const ushort* __restrict__ kv,
                                                   ushort* __restrict__ o) {
  const int blk = blockIdx.x;
  const int bt = blk >> 4;
  const int h = blk & 15;
  const int tid = threadIdx.x;
  const int wave = tid >> 6;
  const int lane = tid & 63;
  const int lr = lane & 15;
  const int lg = lane >> 4;

  __shared__ ushort vt[64][72];
  __shared__ ushort pl[4][16][72];

  const ushort* qbase = q + (size_t)(bt * 64 + wave * 16) * ADIM + h * HD;
  bf16x8 qf[2];
#pragma unroll
  for (int ks = 0; ks < 2; ++ks)
    qf[ks] = *(const bf16x8*)(qbase + (size_t)lr * ADIM + ks * 32 + lg * 8);

  const ushort* kvb = kv + (size_t)bt * NKV * 2048;

  f32x4 accO[4];
#pragma unroll
  for (int n = 0; n < 4; ++n) accO[n] = (f32x4){0.f, 0.f, 0.f, 0.f};
  float mrun[4] = {-1e30f, -1e30f, -1e30f, -1e30f};
  float lrun[4] = {0.f, 0.f, 0.f, 0.f};

  for (int jt = 0; jt < NKV / 64; ++jt) {
    const int j0 = jt * 64;
    __syncthreads();

    {
      int jj = tid >> 2;
      int dbase = (tid & 3) * 16;
#pragma unroll
      for (int half = 0; half < 2; ++half) {
        int d0 = dbase + half * 8;
        bf16x8 vv = *(const bf16x8*)(kvb + (size_t)(j0 + jj) * 2048 + ADIM + h * HD + d0);
#pragma unroll
        for (int e = 0; e < 8; ++e) vt[d0 + e][jj] = ((const ushort*)&vv)[e];
      }
    }

    f32x4 s[4];
#pragma unroll
    for (int nj = 0; nj < 4; ++nj) s[nj] = (f32x4){0.f, 0.f, 0.f, 0.f};
#pragma unroll
    for (int nj = 0; nj < 4; ++nj)
#pragma unroll
      for (int ks = 0; ks < 2; ++ks) {
        bf16x8 kf = *(const bf16x8*)(kvb + (size_t)(j0 + nj * 16 + lr) * 2048 +
                                     h * HD + ks * 32 + lg * 8);
        s[nj] = mfma16(qf[ks], kf, s[nj]);
      }

    float mt[4], corr[4], psum[4];
#pragma unroll
    for (int r = 0; r < 4; ++r)
      mt[r] = fmaxf(fmaxf(s[0][r], s[1][r]), fmaxf(s[2][r], s[3][r]));
#pragma unroll
    for (int off = 1; off < 16; off <<= 1)
#pragma unroll
      for (int r = 0; r < 4; ++r) mt[r] = fmaxf(mt[r], __shfl_xor(mt[r], off, 64));
#pragma unroll
    for (int r = 0; r < 4; ++r) {
      float mn = fmaxf(mrun[r], mt[r]);
      corr[r] = __expf(mrun[r] - mn);
      mrun[r] = mn;
      psum[r] = 0.f;
    }
#pragma unroll
    for (int nj = 0; nj < 4; ++nj)
#pragma unroll
      for (int r = 0; r < 4; ++r) {
        float pv = __expf(s[nj][r] - mrun[r]);
        s[nj][r] = pv;
        psum[r] += pv;
      }
#pragma unroll
    for (int off = 1; off < 16; off <<= 1)
#pragma unroll
      for (int r = 0; r < 4; ++r) psum[r] += __shfl_xor(psum[r], off, 64);
#pragma unroll
    for (int r = 0; r < 4; ++r) lrun[r] = lrun[r] * corr[r] + psum[r];
#pragma unroll
    for (int n = 0; n < 4; ++n)
#pragma unroll
      for (int r = 0; r < 4; ++r) accO[n][r] *= corr[r];

#pragma unroll
    for (int nj = 0; nj < 4; ++nj)
#pragma unroll
      for (int r = 0; r < 4; ++r)
        pl[wave][lg * 4 + r][nj * 16 + lr] = f2bf(s[nj][r]);
    __syncthreads();

    bf16x8 pf[2];
#pragma unroll
    for (int ks = 0; ks < 2; ++ks)
      pf[ks] = *(const bf16x8*)&pl[wave][lr][ks * 32 + lg * 8];
#pragma unroll
    for (int nd = 0; nd < 4; ++nd)
#pragma unroll
      for (int ks = 0; ks < 2; ++ks) {
        bf16x8 vf = *(const bf16x8*)&vt[nd * 16 + lr][ks * 32 + lg * 8];
        accO[nd] = mfma16(pf[ks], vf, accO[nd]);
      }
  }

#pragma unroll
  for (int nd = 0; nd < 4; ++nd)
#pragma unroll
    for (int r = 0; r < 4; ++r) {
      float vv = accO[nd][r] / lrun[r];
      int row = bt * 64 + wave * 16 + lg * 4 + r;
      o[(size_t)row * ADIM + h * HD + nd * 16 + lr] = f2bf(vv);
    }
}

// ---------------------------------------------------------------------------
extern "C" void kernel_launch(void* const* d_in, const int* in_sizes, int n_in,
                              void* d_out, int out_size, void* d_ws, size_t ws_size,
                              hipStream_t stream) {
  const float* latents = (const float*)d_in[0];
  const float* x = (const float*)d_in[1];
  const float* Wq = (const float*)d_in[2];
  const float* Wkv = (const float*)d_in[3];
  const float* Wout = (const float*)d_in[4];
  const float* bout = (const float*)d_in[5];
  const float* lnl_w = (const float*)d_in[6];
  const float* lnl_b = (const float*)d_in[7];
  const float* lnm_w = (const float*)d_in[8];
  const float* lnm_b = (const float*)d_in[9];

  char* ws = (char*)d_ws;
  size_t off = 0;
  auto alloc = [&](size_t bytes) -> void* {
    void* p = ws + off;
    off += (bytes + 255) & ~(size_t)255;
    return p;
  };
  ushort* kvin = (ushort*)alloc((size_t)BT * NKV * D_ * 2);
  ushort* kvo  = (ushort*)alloc((size_t)BT * NKV * 2048 * 2);
  ushort* qb   = (ushort*)alloc((size_t)BT * NLAT * ADIM * 2);
  ushort* ao   = (ushort*)alloc((size_t)BT * NLAT * ADIM * 2);
  ushort* WqT  = (ushort*)alloc((size_t)D_ * ADIM * 2);
  ushort* WkvT = (ushort*)alloc((size_t)D_ * 2 * ADIM * 2);
  ushort* WoutT = (ushort*)alloc((size_t)ADIM * D_ * 2);

  // 96 KB dynamic LDS for gemm256
  static bool attr_set = false;
  (void)attr_set;
  hipFuncSetAttribute((const void*)gemm256,
                      hipFuncAttributeMaxDynamicSharedMemorySize, 98304);

  // 1) weights -> bf16 B^T
  wtrans<<<dim3(ADIM / 64, D_ / 64), 256, 0, stream>>>(Wq, WqT, D_, ADIM);
  wtrans<<<dim3(2 * ADIM / 64, D_ / 64), 256, 0, stream>>>(Wkv, WkvT, D_, 2 * ADIM);
  wtrans<<<dim3(D_ / 64, ADIM / 64), 256, 0, stream>>>(Wout, WoutT, ADIM, D_);

  // 2) LN -> bf16 kv_in
  ln_kernel<<<BT * NKV, 256, 0, stream>>>(latents, x, lnl_w, lnl_b, lnm_w, lnm_b, kvin);

  // 3) q = lat_ln @ Wq (remapped A rows, 0.125 folded)
  gemm_bt<1, 1><<<dim3(ADIM / 128, BT * NLAT / 128), 256, 0, stream>>>(
      kvin, WqT, qb, nullptr, BT * NLAT, ADIM, D_, ADIM);

  // 4) kv = kv_in @ Wkv  — deep-pipelined 256^2 kernel
  gemm256<<<dim3(MT256 * 8), 512, 98304, stream>>>(kvin, WkvT, kvo);

  // 5) attention
  attn_kernel<<<BT * HEADS, 256, 0, stream>>>(qb, kvo, ao);

  // 6) out = ao @ Wout + bout
  gemm_bt<0, 2><<<dim3(D_ / 128, BT * NLAT / 128), 256, 0, stream>>>(
      ao, WoutT, d_out, bout, BT * NLAT, D_, ADIM, D_);
}

// Round 3
// 595.646 us; speedup vs baseline: 1.1268x; 1.0013x over previous
//
#include <hip/hip_runtime.h>
#include <hip/hip_bf16.h>
#include <stdint.h>

// Problem constants
#define B_    8
#define T_    4
#define NLAT  64
#define NMED  2048
#define NKV   2112      // NMED + NLAT
#define D_    1024
#define HEADS 16
#define HD    64
#define ADIM  1024
#define BT    32        // B_*T_

#define GK    1024      // kv-GEMM K
#define GN    2048      // kv-GEMM N
#define GM    67584     // BT*NKV
#define BM_   128
#define BN_   256
#define MT    528       // GM/BM_
#define NT_K  32        // GK/32

typedef __attribute__((ext_vector_type(8))) short bf16x8;
typedef __attribute__((ext_vector_type(4))) float f32x4;

__device__ __forceinline__ ushort f2bf(float f) {
  union { float f; uint32_t u; } v; v.f = f;
  return (ushort)((v.u + 0x7fff + ((v.u >> 16) & 1)) >> 16);
}

__device__ __forceinline__ void gload_lds16(const void* g, void* l) {
  __builtin_amdgcn_global_load_lds(
      (const __attribute__((address_space(1))) void*)g,
      (__attribute__((address_space(3))) void*)l, 16, 0, 0);
}

__device__ __forceinline__ f32x4 mfma16(bf16x8 a, bf16x8 b, f32x4 c) {
  return __builtin_amdgcn_mfma_f32_16x16x32_bf16(a, b, c, 0, 0, 0);
}

// ---------------------------------------------------------------------------
// Weight transpose + f32->bf16: dst[n][k] = src[k][n].  src [K][Nm], 64x64 tiles.
__global__ __launch_bounds__(256) void wtrans(const float* __restrict__ src,
                                              ushort* __restrict__ dst,
                                              int K, int Nm) {
  __shared__ float t[64][65];
  const int tr = blockIdx.y, tc = blockIdx.x;
  const int c = threadIdx.x & 63;
  const int r4 = threadIdx.x >> 6;
#pragma unroll
  for (int rr = 0; rr < 16; ++rr) {
    int r = r4 + rr * 4;
    t[r][c] = src[(size_t)(tr * 64 + r) * Nm + tc * 64 + c];
  }
  __syncthreads();
#pragma unroll
  for (int rr = 0; rr < 16; ++rr) {
    int n = r4 + rr * 4;
    dst[(size_t)(tc * 64 + n) * K + tr * 64 + c] = f2bf(t[c][n]);
  }
}

// ---------------------------------------------------------------------------
// LayerNorm -> bf16, writing concatenated kv_in.
__global__ __launch_bounds__(256) void ln_kernel(
    const float* __restrict__ lat, const float* __restrict__ x,
    const float* __restrict__ lnl_w, const float* __restrict__ lnl_b,
    const float* __restrict__ lnm_w, const float* __restrict__ lnm_b,
    ushort* __restrict__ kvin) {
  const int row = blockIdx.x;
  const int bt = row / NKV;
  const int j = row - bt * NKV;
  const float* src;
  const float* w;
  const float* bb;
  if (j < NMED) {
    src = x + ((size_t)bt * NMED + j) * D_;
    w = lnm_w; bb = lnm_b;
  } else {
    src = lat + ((size_t)bt * NLAT + (j - NMED)) * D_;
    w = lnl_w; bb = lnl_b;
  }
  const int tid = threadIdx.x;
  float4 v = ((const float4*)src)[tid];
  float s = v.x + v.y + v.z + v.w;
  float s2 = v.x * v.x + v.y * v.y + v.z * v.z + v.w * v.w;
#pragma unroll
  for (int off = 1; off < 64; off <<= 1) {
    s += __shfl_xor(s, off, 64);
    s2 += __shfl_xor(s2, off, 64);
  }
  __shared__ float red[8];
  const int wave = tid >> 6;
  if ((tid & 63) == 0) { red[wave] = s; red[4 + wave] = s2; }
  __syncthreads();
  float S = red[0] + red[1] + red[2] + red[3];
  float S2 = red[4] + red[5] + red[6] + red[7];
  const float inv = 1.f / (float)D_;
  float mu = S * inv;
  float var = S2 * inv - mu * mu;
  float rs = rsqrtf(var + 1e-5f);
  float4 wv = ((const float4*)w)[tid];
  float4 bv = ((const float4*)bb)[tid];
  ushort4 ov;
  ov.x = f2bf((v.x - mu) * rs * wv.x + bv.x);
  ov.y = f2bf((v.y - mu) * rs * wv.y + bv.y);
  ov.z = f2bf((v.z - mu) * rs * wv.z + bv.z);
  ov.w = f2bf((v.w - mu) * rs * wv.w + bv.w);
  ((ushort4*)(kvin + (size_t)row * D_))[tid] = ov;
}

// ---------------------------------------------------------------------------
// m97-structure 128x128 GEMM — used for the two SMALL GEMMs (q, out).
// AMODE:  0 = direct rows; 1 = q-GEMM remap (row -> kvin[bt*2112+2048+local])
// OUTMODE:1 = bf16 * 0.125 (q scale); 2 = f32 + bias
template <int AMODE, int OUTMODE>
__global__ __launch_bounds__(256) void gemm_bt(const ushort* __restrict__ A,
                                               const ushort* __restrict__ Bt,
                                               void* __restrict__ C,
                                               const float* __restrict__ bias,
                                               int M, int N, int K, int ldc) {
  __shared__ ushort lsA[128 * 32];
  __shared__ ushort lsB[128 * 32];
  const int tid = threadIdx.x;
  const int lane = tid & 63;
  const int wave = tid >> 6;
  const int brow = blockIdx.y * 128;
  const int bcol = blockIdx.x * 128;
  const int wr = (wave >> 1) * 64;
  const int wc = (wave & 1) * 64;
  const int lr = lane & 15;
  const int lk = (lane >> 4) * 8;

  f32x4 acc[4][4];
#pragma unroll
  for (int m = 0; m < 4; ++m)
#pragma unroll
    for (int n = 0; n < 4; ++n) acc[m][n] = (f32x4){0.f, 0.f, 0.f, 0.f};

  const int wbase = (tid & 192) * 16;

  for (int k0 = 0; k0 < K; k0 += 32) {
#pragma unroll
    for (int i = 0; i < 2; ++i) {
      int idx = i * 256 + tid;
      int r = idx >> 2;
      int cc = (idx & 3) * 8;
      long arow;
      if (AMODE == 1) {
        int gr = brow + r;
        arow = (long)(gr >> 6) * NKV + NMED + (gr & 63);
      } else {
        arow = brow + r;
      }
      gload_lds16(A + arow * (long)K + k0 + cc, (char*)lsA + i * 4096 + wbase);
      gload_lds16(Bt + (long)(bcol + r) * K + k0 + cc, (char*)lsB + i * 4096 + wbase);
    }
    __syncthreads();

    bf16x8 af[4], bf[4];
#pragma unroll
    for (int m = 0; m < 4; ++m)
      af[m] = *(const bf16x8*)&lsA[(wr + m * 16 + lr) * 32 + lk];
#pragma unroll
    for (int n = 0; n < 4; ++n)
      bf[n] = *(const bf16x8*)&lsB[(wc + n * 16 + lr) * 32 + lk];
#pragma unroll
    for (int m = 0; m < 4; ++m)
#pragma unroll
      for (int n = 0; n < 4; ++n) acc[m][n] = mfma16(af[m], bf[n], acc[m][n]);
    __syncthreads();
  }

#pragma unroll
  for (int m = 0; m < 4; ++m) {
#pragma unroll
    for (int n = 0; n < 4; ++n) {
      int row0 = brow + wr + m * 16 + (lane >> 4) * 4;
      int col = bcol + wc + n * 16 + lr;
#pragma unroll
      for (int r = 0; r < 4; ++r) {
        long off = (long)(row0 + r) * ldc + col;
        float v = acc[m][n][r];
        if (OUTMODE == 1) ((ushort*)C)[off] = f2bf(v * 0.125f);
        else ((float*)C)[off] = v + bias[col];
      }
    }
  }
}

// ---------------------------------------------------------------------------
// kv-GEMM: 128x256 tile, BK=32, 8 waves of 64x64, 2 LDS buffers (48 KB) ->
// 2 blocks/CU.  Counted vmcnt(3) pipeline (never drained to 0 in the loop),
// 2 barriers per K-tile, both-sides chunk swizzle, swapped-operand MFMA,
// coalesced ushort4 C-stores, bijective XCD swizzle (4224 = 8*528).
__global__ __launch_bounds__(512, 4) void gemm256(const ushort* __restrict__ A,
                                                  const ushort* __restrict__ Bt,
                                                  ushort* __restrict__ C) {
  __shared__ __align__(16) char smem[2 * 24576];  // per buf: 8 KB A + 16 KB B
  const int tid = threadIdx.x;
  const int lane = tid & 63;
  const int wv = tid >> 6;   // 0..7
  const int wm = wv >> 2;    // 0..1  (M half: 64 rows)
  const int wn = wv & 3;     // 0..3  (N quarter: 64 cols)
  const int lr = lane & 15;
  const int lg = lane >> 4;

  // bijective XCD swizzle: nwg = 4224 = 8 * 528
  const int g = blockIdx.x;
  const int v = (g & 7) * MT + (g >> 3);
  const int bx = v & 7;        // N tile (fast -> A-panel reuse within XCD)
  const int by = v >> 3;       // M tile
  const long brow = (long)by * BM_;
  const int bcol = bx * BN_;

  const int pcx = lg ^ ((lr >> 1) & 3);  // physical 16B-chunk for frag reads

  f32x4 acc[4][4];
#pragma unroll
  for (int m = 0; m < 4; ++m)
#pragma unroll
    for (int n = 0; n < 4; ++n) acc[m][n] = (f32x4){0.f, 0.f, 0.f, 0.f};

  // staging decode: slot s -> row = s>>2, logical chunk = (s&3) ^ ((s>>3)&3)
  const int rA = tid >> 2;
  const int lc = (tid & 3) ^ ((tid >> 3) & 3);   // same for all 3 loads
  const int offA = (tid & ~63) * 16;             // wave-uniform byte base
  const int rB1 = 128 + (tid >> 2);
  const int offB1 = 8192 + offA;

#define STAGE(buf, kt)                                                         \
  {                                                                            \
    long k0 = (long)(kt) * 32;                                                 \
    char* dbA = smem + (buf) * 24576;                                          \
    char* dbB = dbA + 8192;                                                    \
    gload_lds16(A + (brow + rA) * (long)GK + k0 + lc * 8, dbA + offA);         \
    gload_lds16(Bt + (long)(bcol + rA) * GK + k0 + lc * 8, dbB + offA);        \
    gload_lds16(Bt + (long)(bcol + rB1) * GK + k0 + lc * 8, dbB + offB1);      \
  }

  // prologue: tile 0 -> buf 0 (3 loads in flight)
  STAGE(0, 0);

  for (int t = 0; t < NT_K; ++t) {
    const int p = t & 1;
    __builtin_amdgcn_s_barrier();              // (A) prev iter's reads of ~p done
    asm volatile("" ::: "memory");
    const int ts = (t + 1 < NT_K) ? t + 1 : t; // dummy restage at tail
    STAGE(p ^ 1, ts);                          // 3 loads -> other buffer
    asm volatile("s_waitcnt vmcnt(3)" ::: "memory");  // tile t landed; t+1 in flight
    __builtin_amdgcn_s_barrier();              // (B) tile t visible to all waves
    asm volatile("" ::: "memory");

    const char* bufA = smem + p * 24576;
    const char* bufB = bufA + 8192;
    bf16x8 af[4], bf[4];
#pragma unroll
    for (int m = 0; m < 4; ++m) {
      int row = wm * 64 + m * 16 + lr;
      af[m] = *(const bf16x8*)(bufA + row * 64 + pcx * 16);
    }
#pragma unroll
    for (int n = 0; n < 4; ++n) {
      int row = wn * 64 + n * 16 + lr;
      bf[n] = *(const bf16x8*)(bufB + row * 64 + pcx * 16);
    }
    __builtin_amdgcn_s_setprio(1);
#pragma unroll
    for (int m = 0; m < 4; ++m)
#pragma unroll
      for (int n = 0; n < 4; ++n)
        acc[m][n] = mfma16(bf[n], af[m], acc[m][n]);   // swapped operands
    __builtin_amdgcn_s_setprio(0);
  }
#undef STAGE

  // epilogue: lane owns row ...+lr, 4 consecutive cols per frag (ushort4)
#pragma unroll
  for (int m = 0; m < 4; ++m) {
    long row = brow + wm * 64 + m * 16 + lr;
    ushort* crow = C + row * GN + bcol + wn * 64 + lg * 4;
#pragma unroll
    for (int n = 0; n < 4; ++n) {
      ushort4 o;
      o.x = f2bf(acc[m][n][0]);
      o.y = f2bf(acc[m][n][1]);
      o.z = f2bf(acc[m][n][2]);
      o.w = f2bf(acc[m][n][3]);
      *(ushort4*)(crow + n * 16) = o;
    }
  }
}

// ---------------------------------------------------------------------------
// Flash attention: one block per (bt, h). 4 waves x 16 q-rows. 33 j-tiles of 64.
__global__ __launch_bounds__(256) void attn_kernel(const ushort* __restrict__ q,
                                                   const ushort* __restrict__ kv,
                                                   ushort* __restrict__ o) {
  const int blk = blockIdx.x;
  const int bt = blk >> 4;
  const int h = blk & 15;
  const int tid = threadIdx.x;
  const int wave = tid >> 6;
  const int lane = tid & 63;
  const int lr = lane & 15;
  const int lg = lane >> 4;

  __shared__ ushort vt[64][72];
  __shared__ ushort pl[4][16][72];

  const ushort* qbase = q + (size_t)(bt * 64 + wave * 16) * ADIM + h * HD;
  bf16x8 qf[2];
#pragma unroll
  for (int ks = 0; ks < 2; ++ks)
    qf[ks] = *(const bf16x8*)(qbase + (size_t)lr * ADIM + ks * 32 + lg * 8);

  const ushort* kvb = kv + (size_t)bt * NKV * 2048;

  f32x4 accO[4];
#pragma unroll
  for (int n = 0; n < 4; ++n) accO[n] = (f32x4){0.f, 0.f, 0.f, 0.f};
  float mrun[4] = {-1e30f, -1e30f, -1e30f, -1e30f};
  float lrun[4] = {0.f, 0.f, 0.f, 0.f};

  for (int jt = 0; jt < NKV / 64; ++jt) {
    const int j0 = jt * 64;
    __syncthreads();

    {
      int jj = tid >> 2;
      int dbase = (tid & 3) * 16;
#pragma unroll
      for (int half = 0; half < 2; ++half) {
        int d0 = dbase + half * 8;
        bf16x8 vv = *(const bf16x8*)(kvb + (size_t)(j0 + jj) * 2048 + ADIM + h * HD + d0);
#pragma unroll
        for (int e = 0; e < 8; ++e) vt[d0 + e][jj] = ((const ushort*)&vv)[e];
      }
    }

    f32x4 s[4];
#pragma unroll
    for (int nj = 0; nj < 4; ++nj) s[nj] = (f32x4){0.f, 0.f, 0.f, 0.f};
#pragma unroll
    for (int nj = 0; nj < 4; ++nj)
#pragma unroll
      for (int ks = 0; ks < 2; ++ks) {
        bf16x8 kf = *(const bf16x8*)(kvb + (size_t)(j0 + nj * 16 + lr) * 2048 +
                                     h * HD + ks * 32 + lg * 8);
        s[nj] = mfma16(qf[ks], kf, s[nj]);
      }

    float mt[4], corr[4], psum[4];
#pragma unroll
    for (int r = 0; r < 4; ++r)
      mt[r] = fmaxf(fmaxf(s[0][r], s[1][r]), fmaxf(s[2][r], s[3][r]));
#pragma unroll
    for (int off = 1; off < 16; off <<= 1)
#pragma unroll
      for (int r = 0; r < 4; ++r) mt[r] = fmaxf(mt[r], __shfl_xor(mt[r], off, 64));
#pragma unroll
    for (int r = 0; r < 4; ++r) {
      float mn = fmaxf(mrun[r], mt[r]);
      corr[r] = __expf(mrun[r] - mn);
      mrun[r] = mn;
      psum[r] = 0.f;
    }
#pragma unroll
    for (int nj = 0; nj < 4; ++nj)
#pragma unroll
      for (int r = 0; r < 4; ++r) {
        float pv = __expf(s[nj][r] - mrun[r]);
        s[nj][r] = pv;
        psum[r] += pv;
      }
#pragma unroll
    for (int off = 1; off < 16; off <<= 1)
#pragma unroll
      for (int r = 0; r < 4; ++r) psum[r] += __shfl_xor(psum[r], off, 64);
#pragma unroll
    for (int r = 0; r < 4; ++r) lrun[r] = lrun[r] * corr[r] + psum[r];
#pragma unroll
    for (int n = 0; n < 4; ++n)
#pragma unroll
      for (int r = 0; r < 4; ++r) accO[n][r] *= corr[r];

#pragma unroll
    for (int nj = 0; nj < 4; ++nj)
#pragma unroll
      for (int r = 0; r < 4; ++r)
        pl[wave][lg * 4 + r][nj * 16 + lr] = f2bf(s[nj][r]);
    __syncthreads();

    bf16x8 pf[2];
#pragma unroll
    for (int ks = 0; ks < 2; ++ks)
      pf[ks] = *(const bf16x8*)&pl[wave][lr][ks * 32 + lg * 8];
#pragma unroll
    for (int nd = 0; nd < 4; ++nd)
#pragma unroll
      for (int ks = 0; ks < 2; ++ks) {
        bf16x8 vf = *(const bf16x8*)&vt[nd * 16 + lr][ks * 32 + lg * 8];
        accO[nd] = mfma16(pf[ks], vf, accO[nd]);
      }
  }

#pragma unroll
  for (int nd = 0; nd < 4; ++nd)
#pragma unroll
    for (int r = 0; r < 4; ++r) {
      float vv = accO[nd][r] / lrun[r];
      int row = bt * 64 + wave * 16 + lg * 4 + r;
      o[(size_t)row * ADIM + h * HD + nd * 16 + lr] = f2bf(vv);
    }
}

// ---------------------------------------------------------------------------
extern "C" void kernel_launch(void* const* d_in, const int* in_sizes, int n_in,
                              void* d_out, int out_size, void* d_ws, size_t ws_size,
                              hipStream_t stream) {
  const float* latents = (const float*)d_in[0];
  const float* x = (const float*)d_in[1];
  const float* Wq = (const float*)d_in[2];
  const float* Wkv = (const float*)d_in[3];
  const float* Wout = (const float*)d_in[4];
  const float* bout = (const float*)d_in[5];
  const float* lnl_w = (const float*)d_in[6];
  const float* lnl_b = (const float*)d_in[7];
  const float* lnm_w = (const float*)d_in[8];
  const float* lnm_b = (const float*)d_in[9];

  char* ws = (char*)d_ws;
  size_t off = 0;
  auto alloc = [&](size_t bytes) -> void* {
    void* p = ws + off;
    off += (bytes + 255) & ~(size_t)255;
    return p;
  };
  ushort* kvin = (ushort*)alloc((size_t)BT * NKV * D_ * 2);
  ushort* kvo  = (ushort*)alloc((size_t)BT * NKV * 2048 * 2);
  ushort* qb   = (ushort*)alloc((size_t)BT * NLAT * ADIM * 2);
  ushort* ao   = (ushort*)alloc((size_t)BT * NLAT * ADIM * 2);
  ushort* WqT  = (ushort*)alloc((size_t)D_ * ADIM * 2);
  ushort* WkvT = (ushort*)alloc((size_t)D_ * 2 * ADIM * 2);
  ushort* WoutT = (ushort*)alloc((size_t)ADIM * D_ * 2);

  // 1) weights -> bf16 B^T
  wtrans<<<dim3(ADIM / 64, D_ / 64), 256, 0, stream>>>(Wq, WqT, D_, ADIM);
  wtrans<<<dim3(2 * ADIM / 64, D_ / 64), 256, 0, stream>>>(Wkv, WkvT, D_, 2 * ADIM);
  wtrans<<<dim3(D_ / 64, ADIM / 64), 256, 0, stream>>>(Wout, WoutT, ADIM, D_);

  // 2) LN -> bf16 kv_in
  ln_kernel<<<BT * NKV, 256, 0, stream>>>(latents, x, lnl_w, lnl_b, lnm_w, lnm_b, kvin);

  // 3) q = lat_ln @ Wq (remapped A rows, 0.125 folded)
  gemm_bt<1, 1><<<dim3(ADIM / 128, BT * NLAT / 128), 256, 0, stream>>>(
      kvin, WqT, qb, nullptr, BT * NLAT, ADIM, D_, ADIM);

  // 4) kv = kv_in @ Wkv  — 128x256, 2 blocks/CU, counted-vmcnt pipeline
  gemm256<<<dim3(MT * 8), 512, 0, stream>>>(kvin, WkvT, kvo);

  // 5) attention
  attn_kernel<<<BT * HEADS, 256, 0, stream>>>(qb, kvo, ao);

  // 6) out = ao @ Wout + bout
  gemm_bt<0, 2><<<dim3(D_ / 128, BT * NLAT / 128), 256, 0, stream>>>(
      ao, WoutT, d_out, bout, BT * NLAT, D_, ADIM, D_);
}